// Round 1
// baseline (27.386 us; speedup 1.0000x reference)
//
#include <hip/hip_runtime.h>
#include <math.h>

namespace {
constexpr int kB = 64;
constexpr int kD = 16;
constexpr int kT = 256;
constexpr int kR = 192;
constexpr float kHours = 48.0f;

__global__ __launch_bounds__(192, 4)
void interp_kernel(const float* __restrict__ x,
                   const float* __restrict__ kern,
                   float* __restrict__ out) {
  __shared__ float sd[kT];
  __shared__ float slm[kT];
  __shared__ float sx[kT];

  const int bc = blockIdx.x;        // b * kD + c
  const int b = bc >> 4;
  const int c = bc & 15;
  const int tid = threadIdx.x;      // 0..191 == ref point index

  const float* vals = x + ((size_t)b * (4 * kD) + c) * kT;
  const float* mrow = vals + (size_t)kD * kT;        // mask channel
  const float* drow = vals + (size_t)(2 * kD) * kT;  // timestamp channel

  for (int t = tid; t < kT; t += 192) {
    sx[t]  = vals[t];
    slm[t] = logf(fmaxf(mrow[t], 1e-30f));
    sd[t]  = drow[t];
  }
  const float alpha = log1pf(__expf(kern[c]));  // softplus
  __syncthreads();

  const float rt = (kHours / (float)(kR - 1)) * (float)tid;

  // ---- pass 1: minDD = min_t (d_t - rt)^2 (safe logsumexp offset for both scales)
  float mn0 = 1e30f, mn1 = 1e30f, mn2 = 1e30f, mn3 = 1e30f;
#pragma unroll 8
  for (int t = 0; t < kT; t += 4) {
    const float4 d4 = *reinterpret_cast<const float4*>(&sd[t]);
    float u;
    u = d4.x - rt; mn0 = fminf(mn0, u * u);
    u = d4.y - rt; mn1 = fminf(mn1, u * u);
    u = d4.z - rt; mn2 = fminf(mn2, u * u);
    u = d4.w - rt; mn3 = fminf(mn3, u * u);
  }
  const float minDD = fminf(fminf(mn0, mn1), fminf(mn2, mn3));

  const float na1  = -alpha;
  const float na10 = -10.0f * alpha;
  const float M1   = na1 * minDD;   // >= true max of s1; true max >= M1 - 69.08
  const float M10  = na10 * minDD;

  // ---- pass 2: two online softmaxes with fixed offsets
  float s1a[4]  = {0.f, 0.f, 0.f, 0.f};
  float y1a[4]  = {0.f, 0.f, 0.f, 0.f};
  float s10a[4] = {0.f, 0.f, 0.f, 0.f};
  float y10a[4] = {0.f, 0.f, 0.f, 0.f};

#pragma unroll 4
  for (int t = 0; t < kT; t += 4) {
    const float4 d4 = *reinterpret_cast<const float4*>(&sd[t]);
    const float4 m4 = *reinterpret_cast<const float4*>(&slm[t]);
    const float4 x4 = *reinterpret_cast<const float4*>(&sx[t]);
#define STEP(i, DC, MC, XC)                                 \
    {                                                       \
      float dt  = (DC) - rt;                                \
      float dd  = dt * dt;                                  \
      float e1  = __expf(fmaf(na1,  dd, (MC)) - M1);        \
      float e10 = __expf(fmaf(na10, dd, (MC)) - M10);       \
      s1a[i]  += e1;   y1a[i]  = fmaf(e1,  (XC), y1a[i]);   \
      s10a[i] += e10;  y10a[i] = fmaf(e10, (XC), y10a[i]);  \
    }
    STEP(0, d4.x, m4.x, x4.x)
    STEP(1, d4.y, m4.y, x4.y)
    STEP(2, d4.z, m4.z, x4.z)
    STEP(3, d4.w, m4.w, x4.w)
#undef STEP
  }

  const float sum1  = (s1a[0] + s1a[1]) + (s1a[2] + s1a[3]);
  const float acc1  = (y1a[0] + y1a[1]) + (y1a[2] + y1a[3]);
  const float sum10 = (s10a[0] + s10a[1]) + (s10a[2] + s10a[3]);
  const float acc10 = (y10a[0] + y10a[1]) + (y10a[2] + y10a[3]);

  float* ob = out + ((size_t)b * (3 * kD)) * kR;
  ob[(size_t)c * kR + tid]            = acc1 / sum1;        // y
  ob[(size_t)(kD + c) * kR + tid]     = M1 + logf(sum1);    // w (logsumexp)
  ob[(size_t)(2 * kD + c) * kR + tid] = acc10 / sum10;      // y_trans
}
}  // namespace

extern "C" void kernel_launch(void* const* d_in, const int* in_sizes, int n_in,
                              void* d_out, int out_size, void* d_ws, size_t ws_size,
                              hipStream_t stream) {
  const float* x    = (const float*)d_in[0];
  const float* kern = (const float*)d_in[1];
  float* out        = (float*)d_out;
  interp_kernel<<<dim3(kB * kD), dim3(192), 0, stream>>>(x, kern, out);
}

// Round 2
// 21.523 us; speedup vs baseline: 1.2724x; 1.2724x over previous
//
#include <hip/hip_runtime.h>
#include <math.h>

namespace {
constexpr int kB = 64;
constexpr int kD = 16;
constexpr int kT = 256;
constexpr int kR = 192;
constexpr float kHours = 48.0f;

typedef float f32x2 __attribute__((ext_vector_type(2)));
typedef float f32x4 __attribute__((ext_vector_type(4)));

__device__ __forceinline__ float fast_exp2(float v) {
#if __has_builtin(__builtin_amdgcn_exp2f)
  return __builtin_amdgcn_exp2f(v);
#else
  return __expf(v * 0.6931471805599453f);
#endif
}

__global__ __launch_bounds__(192)
void interp_kernel(const float* __restrict__ x,
                   const float* __restrict__ kern,
                   float* __restrict__ out) {
  __shared__ float sd[kT];   // timestamps d
  __shared__ float smc[kT];  // mc  = max(m, 1e-30)
  __shared__ float smx[kT];  // mcx = mc * x

  const int bc = blockIdx.x;  // b * kD + c
  const int b = bc >> 4;
  const int c = bc & 15;
  const int tid = threadIdx.x;  // ref point index

  const float* vals = x + ((size_t)b * (4 * kD) + c) * kT;
  const float* mrow = vals + (size_t)kD * kT;        // mask channel
  const float* drow = vals + (size_t)(2 * kD) * kT;  // timestamp channel

  for (int t = tid; t < kT; t += 192) {
    const float mc = fmaxf(mrow[t], 1e-30f);
    smc[t] = mc;
    smx[t] = mc * vals[t];
    sd[t]  = drow[t];
  }
  // stable softplus (evaluated once; kernel[c]==0 in practice)
  const float kv = kern[c];
  const float alpha = fmaxf(kv, 0.0f) + log1pf(__expf(-fabsf(kv)));
  __syncthreads();

  const float rt = (kHours / (float)(kR - 1)) * (float)tid;

  // ---- pass 1: minDD = min_t (d_t - rt)^2  (over ALL t => p <= 1 below)
  f32x4 mn4 = {1e30f, 1e30f, 1e30f, 1e30f};
  const f32x4 rt4 = {rt, rt, rt, rt};
#pragma unroll 8
  for (int t = 0; t < kT; t += 4) {
    const f32x4 d4 = *reinterpret_cast<const f32x4*>(&sd[t]);
    const f32x4 u = d4 - rt4;
    mn4 = __builtin_elementwise_min(mn4, u * u);
  }
  const float minDD = fminf(fminf(mn4.x, mn4.y), fminf(mn4.z, mn4.w));

  const float a1 = alpha * 1.4426950408889634f;  // alpha * log2(e)
  const f32x2 na1_2 = {-a1, -a1};
  const float c1 = a1 * minDD;
  const f32x2 c1_2 = {c1, c1};
  const f32x2 rt2 = {rt, rt};

  // ---- pass 2: p = exp2(-a1*(dd - minDD)) in (0,1]; e1 = p*mc, e10 = p^10*mc
  f32x2 s1v = {0.f, 0.f}, y1v = {0.f, 0.f};
  f32x2 s10v = {0.f, 0.f}, y10v = {0.f, 0.f};

#pragma unroll 4
  for (int t = 0; t < kT; t += 2) {
    const f32x2 d2  = *reinterpret_cast<const f32x2*>(&sd[t]);
    const f32x2 mc2 = *reinterpret_cast<const f32x2*>(&smc[t]);
    const f32x2 mx2 = *reinterpret_cast<const f32x2*>(&smx[t]);

    const f32x2 dt  = d2 - rt2;                              // pk_add(neg)
    const f32x2 q   = dt * na1_2;                            // pk_mul
    const f32x2 arg = __builtin_elementwise_fma(q, dt, c1_2);// pk_fma: -a1*dd + a1*minDD

    f32x2 p;
    p.x = fast_exp2(arg.x);
    p.y = fast_exp2(arg.y);

    const f32x2 p2  = p * p;
    const f32x2 p4  = p2 * p2;
    const f32x2 p8  = p4 * p4;
    const f32x2 p10 = p8 * p2;

    s1v  = __builtin_elementwise_fma(p,   mc2, s1v);
    y1v  = __builtin_elementwise_fma(p,   mx2, y1v);
    s10v = __builtin_elementwise_fma(p10, mc2, s10v);
    y10v = __builtin_elementwise_fma(p10, mx2, y10v);
  }

  const float sum1  = s1v.x + s1v.y;
  const float acc1  = y1v.x + y1v.y;
  const float sum10 = s10v.x + s10v.y;
  const float acc10 = y10v.x + y10v.y;

  float* ob = out + ((size_t)b * (3 * kD)) * kR;
  ob[(size_t)c * kR + tid]            = acc1 / sum1;                  // y
  ob[(size_t)(kD + c) * kR + tid]     = logf(sum1) - alpha * minDD;   // w
  ob[(size_t)(2 * kD + c) * kR + tid] = acc10 / sum10;                // y_trans
}
}  // namespace

extern "C" void kernel_launch(void* const* d_in, const int* in_sizes, int n_in,
                              void* d_out, int out_size, void* d_ws, size_t ws_size,
                              hipStream_t stream) {
  const float* x    = (const float*)d_in[0];
  const float* kern = (const float*)d_in[1];
  float* out        = (float*)d_out;
  interp_kernel<<<dim3(kB * kD), dim3(192), 0, stream>>>(x, kern, out);
}

// Round 3
// 20.742 us; speedup vs baseline: 1.3203x; 1.0377x over previous
//
#include <hip/hip_runtime.h>
#include <math.h>

namespace {
constexpr int kB = 64, kD = 16, kT = 256, kR = 192;
constexpr float kHours = 48.0f;

typedef float f32x2 __attribute__((ext_vector_type(2)));
typedef float f32x4 __attribute__((ext_vector_type(4)));

__device__ __forceinline__ float fast_exp2(float v) {
  return __builtin_amdgcn_exp2f(v);
}

__global__ __launch_bounds__(384, 6)
void interp_kernel(const float* __restrict__ x,
                   const float* __restrict__ kern,
                   float* __restrict__ out) {
  // sPQ[t/2] = {P_t, P_{t+1}, Q_t, Q_{t+1}},  P = -a1*d^2, Q = 2*a1*d
  // sMM[t/2] = {mc_t, mc_{t+1}, mx_t, mx_{t+1}}, mc = max(m,1e-30), mx = mc*x
  __shared__ f32x4 sPQ[kT / 2];
  __shared__ f32x4 sMM[kT / 2];
  __shared__ f32x4 sRed[4][kR];

  const int bc = blockIdx.x;
  const int b = bc >> 4, c = bc & 15;
  const int tid = threadIdx.x;

  const float* vals = x + ((size_t)b * (4 * kD) + c) * kT;
  const float* mrow = vals + (size_t)kD * kT;        // mask channel
  const float* drow = vals + (size_t)(2 * kD) * kT;  // timestamp channel

  // stable softplus; a1 = alpha * log2(e)
  const float kv = kern[c];
  const float alpha = fmaxf(kv, 0.0f) + log1pf(__expf(-fabsf(kv)));
  const float a1 = alpha * 1.4426950408889634f;

  if (tid < 128) {  // PQ producer: pair slot tid -> t = 2*tid, 2*tid+1
    const int t = tid * 2;
    const float2 d2 = *reinterpret_cast<const float2*>(&drow[t]);
    const float q0 = a1 * d2.x, q1 = a1 * d2.y;
    sPQ[tid] = (f32x4){-q0 * d2.x, -q1 * d2.y, q0 + q0, q1 + q1};
  } else if (tid < 256) {  // MM producer
    const int p = tid - 128;
    const int t = p * 2;
    const float2 m2 = *reinterpret_cast<const float2*>(&mrow[t]);
    const float2 v2 = *reinterpret_cast<const float2*>(&vals[t]);
    const float mc0 = fmaxf(m2.x, 1e-30f), mc1 = fmaxf(m2.y, 1e-30f);
    sMM[p] = (f32x4){mc0, mc1, mc0 * v2.x, mc1 * v2.y};
  }
  __syncthreads();

  // thread (h, i): t-quarter h (32 pair-slots), ref points rA=i, rB=i+96
  const int h = tid / 96;
  const int i = tid - h * 96;
  const float step = kHours / (float)(kR - 1);
  const float rtA = step * (float)i;
  const float rtB = step * (float)(i + 96);
  const f32x2 rtA2 = {rtA, rtA}, rtB2 = {rtB, rtB};
  const float KA = -a1 * rtA * rtA, KB = -a1 * rtB * rtB;
  const f32x2 KA2 = {KA, KA}, KB2 = {KB, KB};

  f32x2 s1A = {0.f, 0.f}, y1A = {0.f, 0.f}, s10A = {0.f, 0.f}, y10A = {0.f, 0.f};
  f32x2 s1B = {0.f, 0.f}, y1B = {0.f, 0.f}, s10B = {0.f, 0.f}, y10B = {0.f, 0.f};

  const int p0 = h * 32;
#pragma unroll 8
  for (int p = p0; p < p0 + 32; ++p) {
    const f32x4 pq = sPQ[p];
    const f32x4 mm = sMM[p];
    const f32x2 P = pq.lo, Q = pq.hi;
    const f32x2 mc = mm.lo, mx = mm.hi;

    const f32x2 argA = __builtin_elementwise_fma(Q, rtA2, P) + KA2;
    const f32x2 argB = __builtin_elementwise_fma(Q, rtB2, P) + KB2;

    f32x2 pA, pB;
    pA.x = fast_exp2(argA.x);
    pA.y = fast_exp2(argA.y);
    pB.x = fast_exp2(argB.x);
    pB.y = fast_exp2(argB.y);

    const f32x2 pA2 = pA * pA, pA4 = pA2 * pA2, pA8 = pA4 * pA4, pA10 = pA8 * pA2;
    const f32x2 pB2 = pB * pB, pB4 = pB2 * pB2, pB8 = pB4 * pB4, pB10 = pB8 * pB2;

    s1A  = __builtin_elementwise_fma(pA,   mc, s1A);
    y1A  = __builtin_elementwise_fma(pA,   mx, y1A);
    s10A = __builtin_elementwise_fma(pA10, mc, s10A);
    y10A = __builtin_elementwise_fma(pA10, mx, y10A);
    s1B  = __builtin_elementwise_fma(pB,   mc, s1B);
    y1B  = __builtin_elementwise_fma(pB,   mx, y1B);
    s10B = __builtin_elementwise_fma(pB10, mc, s10B);
    y10B = __builtin_elementwise_fma(pB10, mx, y10B);
  }

  sRed[h][i]      = (f32x4){s1A.x + s1A.y, y1A.x + y1A.y, s10A.x + s10A.y, y10A.x + y10A.y};
  sRed[h][i + 96] = (f32x4){s1B.x + s1B.y, y1B.x + y1B.y, s10B.x + s10B.y, y10B.x + y10B.y};
  __syncthreads();

  if (tid < kR) {
    const f32x4 v0 = sRed[0][tid], v1 = sRed[1][tid], v2 = sRed[2][tid], v3 = sRed[3][tid];
    const float sum1  = (v0.x + v1.x) + (v2.x + v3.x);
    const float acc1  = (v0.y + v1.y) + (v2.y + v3.y);
    const float sum10 = (v0.z + v1.z) + (v2.z + v3.z);
    const float acc10 = (v0.w + v1.w) + (v2.w + v3.w);

    float* ob = out + (size_t)b * (3 * kD) * kR;
    ob[(size_t)c * kR + tid]              = acc1 / sum1;    // y
    ob[(size_t)(kD + c) * kR + tid]       = logf(sum1);     // w (logsumexp, no offset)
    ob[(size_t)(2 * kD + c) * kR + tid]   = acc10 / sum10;  // y_trans
  }
}
}  // namespace

extern "C" void kernel_launch(void* const* d_in, const int* in_sizes, int n_in,
                              void* d_out, int out_size, void* d_ws, size_t ws_size,
                              hipStream_t stream) {
  const float* x    = (const float*)d_in[0];
  const float* kern = (const float*)d_in[1];
  float* out        = (float*)d_out;
  interp_kernel<<<dim3(kB * kD), dim3(384), 0, stream>>>(x, kern, out);
}

// Round 4
// 16.353 us; speedup vs baseline: 1.6747x; 1.2684x over previous
//
#include <hip/hip_runtime.h>
#include <math.h>

namespace {
constexpr int kB = 64, kD = 16, kT = 256, kR = 192;
constexpr float kHours = 48.0f;
constexpr float kLog2e = 1.4426950408889634f;
// exclusion cutoff in log2 units: 69.08 nats (1e-30 mask floor) + ~11 nats slack
constexpr float kCut2 = 116.0f;

typedef float f32x2 __attribute__((ext_vector_type(2)));
typedef float f32x4 __attribute__((ext_vector_type(4)));

__global__ __launch_bounds__(384, 6)
void interp_kernel(const float* __restrict__ x,
                   const float* __restrict__ kern,
                   float* __restrict__ out) {
  // pair p: sPQ4[p] = {P_{2p}, P_{2p+1}, Q_{2p}, Q_{2p+1}}  (P = -a1*d^2, Q = 2*a1*d)
  //         sMM4[p] = {mc_{2p}, mc_{2p+1}, mx_{2p}, mx_{2p+1}}
  __shared__ f32x4 sPQ4[kT / 2];
  __shared__ f32x4 sMM4[kT / 2];
  __shared__ float sGmax[4];
  __shared__ int sCnt[12];
  float* sPQ = reinterpret_cast<float*>(sPQ4);
  float* sMM = reinterpret_cast<float*>(sMM4);

  const int tid = threadIdx.x;
  const int bc = blockIdx.x;
  const int b = bc >> 4, c = bc & 15;

  const float* vals = x + ((size_t)b * (4 * kD) + c) * kT;
  const float* mrow = vals + (size_t)kD * kT;
  const float* drow = vals + (size_t)(2 * kD) * kT;

  const float kv = kern[c];
  const float alpha = fmaxf(kv, 0.0f) + log1pf(__expf(-fabsf(kv)));
  const float a1 = alpha * kLog2e;  // base-2 rate

  float d_reg = 1e30f;
  if (tid < kT) {
    const int t = tid;
    const float d = drow[t];
    d_reg = d;
    const float mv = mrow[t];
    const float xv = vals[t];
    const float dn = (t < kT - 1) ? drow[t + 1] : kHours;

    const int p = t >> 1, o = t & 1;
    const float q = a1 * d;
    sPQ[4 * p + o]     = -q * d;   // P
    sPQ[4 * p + 2 + o] = q + q;    // Q
    const float mc = fmaxf(mv, 1e-30f);
    sMM[4 * p + o]     = mc;
    sMM[4 * p + 2 + o] = mc * xv;

    // halfW: bound on distance from any rt in [0,48] to its nearest d
    float g = (t < kT - 1) ? 0.5f * (dn - d) : (kHours - d);
    if (t == 0) g = fmaxf(g, d);
#pragma unroll
    for (int s = 1; s < 64; s <<= 1) g = fmaxf(g, __shfl_xor(g, s));
    if ((tid & 63) == 0) sGmax[tid >> 6] = g;
  } else if (tid < kT + 12) {
    sCnt[tid - kT] = 0;
  }
  __syncthreads();

  const float halfW = fmaxf(fmaxf(sGmax[0], sGmax[1]), fmaxf(sGmax[2], sGmax[3]));
  const float W = sqrtf(halfW * halfW + kCut2 / a1);
  const float step = kHours / (float)(kR - 1);

  // per-wave t-window via ballot counts: wave k covers r in [32k, 32k+31]
  if (tid < kT) {
#pragma unroll
    for (int k = 0; k < 6; ++k) {
      const float lo = step * (float)(32 * k) - W;
      const float hi = step * (float)(32 * k + 31) + W;
      const unsigned long long blo = __ballot(d_reg < lo);
      const unsigned long long bhi = __ballot(d_reg < hi);
      if ((tid & 63) == 0) {
        atomicAdd(&sCnt[k], (int)__popcll(blo));
        atomicAdd(&sCnt[6 + k], (int)__popcll(bhi));
      }
    }
  }
  __syncthreads();

  const int w = tid >> 6;        // wave id 0..5
  const int lane = tid & 63;
  const int ri = 32 * w + (lane >> 1);
  const int parity = lane & 1;
  const float rt = step * (float)ri;
  const f32x2 rt2 = {rt, rt};
  const float K = -a1 * rt * rt;
  const f32x2 K2 = {K, K};

  const int t0 = sCnt[w];
  const int t1 = sCnt[6 + w];
  const int p0 = t0 >> 1;
  const int p1 = (t1 + 1) >> 1;

  f32x2 s1 = {0.f, 0.f}, y1 = {0.f, 0.f}, s10 = {0.f, 0.f}, y10 = {0.f, 0.f};

#pragma unroll 4
  for (int p = p0 + parity; p < p1; p += 2) {
    const f32x4 pq = sPQ4[p];
    const f32x4 mm = sMM4[p];
    const f32x2 arg = __builtin_elementwise_fma(pq.hi, rt2, pq.lo) + K2;
    f32x2 pe;
    pe.x = __builtin_amdgcn_exp2f(arg.x);
    pe.y = __builtin_amdgcn_exp2f(arg.y);
    const f32x2 pe2 = pe * pe, pe4 = pe2 * pe2, pe8 = pe4 * pe4, pe10 = pe8 * pe2;
    s1  = __builtin_elementwise_fma(pe,   mm.lo, s1);
    y1  = __builtin_elementwise_fma(pe,   mm.hi, y1);
    s10 = __builtin_elementwise_fma(pe10, mm.lo, s10);
    y10 = __builtin_elementwise_fma(pe10, mm.hi, y10);
  }

  float S1 = s1.x + s1.y, Y1 = y1.x + y1.y;
  float S10 = s10.x + s10.y, Y10 = y10.x + y10.y;
  S1 += __shfl_xor(S1, 1);
  Y1 += __shfl_xor(Y1, 1);
  S10 += __shfl_xor(S10, 1);
  Y10 += __shfl_xor(Y10, 1);

  if (parity == 0) {
    float* ob = out + (size_t)b * (3 * kD) * kR;
    ob[(size_t)c * kR + ri]            = Y1 / S1;
    ob[(size_t)(kD + c) * kR + ri]     = logf(S1);
    ob[(size_t)(2 * kD + c) * kR + ri] = Y10 / S10;
  }
}
}  // namespace

extern "C" void kernel_launch(void* const* d_in, const int* in_sizes, int n_in,
                              void* d_out, int out_size, void* d_ws, size_t ws_size,
                              hipStream_t stream) {
  const float* x    = (const float*)d_in[0];
  const float* kern = (const float*)d_in[1];
  float* out        = (float*)d_out;
  interp_kernel<<<dim3(kB * kD), dim3(384), 0, stream>>>(x, kern, out);
}

// Round 5
// 15.428 us; speedup vs baseline: 1.7751x; 1.0600x over previous
//
#include <hip/hip_runtime.h>
#include <math.h>

namespace {
constexpr int kB = 64, kD = 16, kT = 256, kR = 192;
constexpr float kHours = 48.0f;
constexpr float kLog2e = 1.4426950408889634f;
// exclusion cutoff (log2) vs nearest-UNMASKED retained term: rel err <= ~150*2^-33 ~ 2e-8
constexpr float kCutU = 33.0f;

typedef float f32x2 __attribute__((ext_vector_type(2)));
typedef float f32x4 __attribute__((ext_vector_type(4)));

__global__ __launch_bounds__(384, 6)
void interp_kernel(const float* __restrict__ x,
                   const float* __restrict__ kern,
                   float* __restrict__ out) {
  // pair p: sPQ4[p] = {P_{2p}, P_{2p+1}, Q_{2p}, Q_{2p+1}}  (P = -a1*d^2, Q = 2*a1*d)
  //         sMM4[p] = {mc_{2p}, mc_{2p+1}, mx_{2p}, mx_{2p+1}}
  __shared__ f32x4 sPQ4[kT / 2];
  __shared__ f32x4 sMM4[kT / 2];
  __shared__ float sInfo[4][4];  // per producer wave: {maxgap, firstU, lastU, any}
  __shared__ int sCnt[12];
  float* sPQ = reinterpret_cast<float*>(sPQ4);
  float* sMM = reinterpret_cast<float*>(sMM4);

  const int tid = threadIdx.x;
  const int bc = blockIdx.x;
  const int b = bc >> 4, c = bc & 15;

  const float* vals = x + ((size_t)b * (4 * kD) + c) * kT;
  const float* mrow = vals + (size_t)kD * kT;
  const float* drow = vals + (size_t)(2 * kD) * kT;

  const float kv = kern[c];
  const float alpha = fmaxf(kv, 0.0f) + log1pf(__expf(-fabsf(kv)));
  const float a1 = alpha * kLog2e;  // base-2 rate (== 1.0 for kernel==0)

  float d_reg = 1e30f;
  if (tid < kT) {
    const float d = drow[tid];
    d_reg = d;
    const float mv = mrow[tid];
    const float xv = vals[tid];

    const int p = tid >> 1, o = tid & 1;
    const float q = a1 * d;
    sPQ[4 * p + o]     = -q * d;
    sPQ[4 * p + 2 + o] = q + q;
    const float mc = fmaxf(mv, 1e-30f);
    sMM[4 * p + o]     = mc;
    sMM[4 * p + 2 + o] = mc * xv;

    // unmasked-gap stats within this 64-t wave
    const bool unm = (mv >= 0.5f);
    const unsigned long long bm = __ballot(unm);
    const int l = tid & 63;
    const unsigned long long above = bm & (~1ull << l);
    const int nxt = above ? (__ffsll((long long)above) - 1) : -1;
    const float dnext = __shfl(d, nxt < 0 ? l : nxt);
    float g = (unm && nxt >= 0) ? (dnext - d) : 0.0f;
#pragma unroll
    for (int s = 1; s < 64; s <<= 1) g = fmaxf(g, __shfl_xor(g, s));
    const int fi = bm ? (__ffsll((long long)bm) - 1) : 0;
    const int li = bm ? (63 - __clzll((long long)bm)) : 0;
    const float dF = __shfl(d, fi);
    const float dL = __shfl(d, li);
    if (l == 0) {
      const int w4 = tid >> 6;
      sInfo[w4][0] = g;
      sInfo[w4][1] = bm ? dF : 1e30f;
      sInfo[w4][2] = bm ? dL : -1e30f;
      sInfo[w4][3] = bm ? 1.0f : 0.0f;
    }
  } else if (tid < kT + 12) {
    sCnt[tid - kT] = 0;
  }
  __syncthreads();

  // compose cross-wave unmasked stats -> halfWu bound on nearest-unmasked distance
  float maxgap = 0.0f, firstU = 1e30f, lastU = -1e30f;
#pragma unroll
  for (int k = 0; k < 4; ++k) {
    if (sInfo[k][3] > 0.0f) {
      maxgap = fmaxf(maxgap, sInfo[k][0]);
      if (lastU > -1e29f) maxgap = fmaxf(maxgap, sInfo[k][1] - lastU);
      if (firstU > 1e29f) firstU = sInfo[k][1];
      lastU = sInfo[k][2];
    }
  }
  const float halfWu = fmaxf(fmaxf(firstU, kHours - lastU), 0.5f * maxgap);
  const float W = sqrtf(halfWu * halfWu + kCutU / a1);
  const float step = kHours / (float)(kR - 1);

  // per-wave t-window via ballot counts: wave k covers r in [32k, 32k+31]
  if (tid < kT) {
#pragma unroll
    for (int k = 0; k < 6; ++k) {
      const float lo = step * (float)(32 * k) - W;
      const float hi = step * (float)(32 * k + 31) + W;
      const unsigned long long blo = __ballot(d_reg < lo);
      const unsigned long long bhi = __ballot(d_reg < hi);
      if ((tid & 63) == 0) {
        atomicAdd(&sCnt[k], (int)__popcll(blo));
        atomicAdd(&sCnt[6 + k], (int)__popcll(bhi));
      }
    }
  }
  __syncthreads();

  const int w = tid >> 6;  // wave id 0..5
  const int lane = tid & 63;
  const int ri = 32 * w + (lane >> 1);
  const int parity = lane & 1;
  const float rt = step * (float)ri;
  const f32x2 rt2 = {rt, rt};
  const float K = -a1 * rt * rt;
  const f32x2 K2 = {K, K};

  const int t0 = sCnt[w];
  const int t1 = sCnt[6 + w];
  const int p0 = t0 >> 1;
  const int p1 = (t1 + 1) >> 1;

  f32x2 s1 = {0.f, 0.f}, y1 = {0.f, 0.f}, s10 = {0.f, 0.f}, y10 = {0.f, 0.f};

#pragma unroll 4
  for (int p = p0 + parity; p < p1; p += 2) {
    const f32x4 pq = sPQ4[p];
    const f32x4 mm = sMM4[p];
    const f32x2 arg = __builtin_elementwise_fma(pq.hi, rt2, pq.lo) + K2;
    f32x2 pe;
    pe.x = __builtin_amdgcn_exp2f(arg.x);
    pe.y = __builtin_amdgcn_exp2f(arg.y);
    const f32x2 pe2 = pe * pe, pe4 = pe2 * pe2, pe8 = pe4 * pe4, pe10 = pe8 * pe2;
    s1  = __builtin_elementwise_fma(pe,   mm.lo, s1);
    y1  = __builtin_elementwise_fma(pe,   mm.hi, y1);
    s10 = __builtin_elementwise_fma(pe10, mm.lo, s10);
    y10 = __builtin_elementwise_fma(pe10, mm.hi, y10);
  }

  float S1 = s1.x + s1.y, Y1 = y1.x + y1.y;
  float S10 = s10.x + s10.y, Y10 = y10.x + y10.y;
  S1 += __shfl_xor(S1, 1);
  Y1 += __shfl_xor(Y1, 1);
  S10 += __shfl_xor(S10, 1);
  Y10 += __shfl_xor(Y10, 1);

  if (parity == 0) {
    float* ob = out + (size_t)b * (3 * kD) * kR;
    ob[(size_t)c * kR + ri]            = Y1 / S1;
    ob[(size_t)(kD + c) * kR + ri]     = logf(S1);
    ob[(size_t)(2 * kD + c) * kR + ri] = Y10 / S10;
  }
}
}  // namespace

extern "C" void kernel_launch(void* const* d_in, const int* in_sizes, int n_in,
                              void* d_out, int out_size, void* d_ws, size_t ws_size,
                              hipStream_t stream) {
  const float* x    = (const float*)d_in[0];
  const float* kern = (const float*)d_in[1];
  float* out        = (float*)d_out;
  interp_kernel<<<dim3(kB * kD), dim3(384), 0, stream>>>(x, kern, out);
}